// Round 6
// baseline (259.888 us; speedup 1.0000x reference)
//
#include <hip/hip_runtime.h>
#include <stdint.h>

// RNN1: B=4096,T=256,E=27,H=64.
// a_{t+1} = tanh(a_t @ Waa^T + x_t @ Wax^T + ba), x_t = word[:,t-1,:] (0 at t=0)
// y[:,t,:] = a_{t+1} @ Wy^T + by
//
// Round 6 = round 5 with weight fragments pinned in AGPRs ("+a" asm, IN-LOOP).
// r5 evidence: VGPR_Count=136 (need ~250 for all weights resident) and dur
// unchanged 267us -> allocator spill/reloads weight frags from scratch every
// step (~15-20 dependent buffer_loads/step on a single wave = ~2000 cyc/step
// stall). gfx950 MFMA reads A/B directly from AGPRs (unified file), so "+a"
// pins move the 96 weight regs out of the arch-VGPR budget entirely; in-loop
// use-def pins make spilling cost store+load per iter -> allocator keeps them.
//
// TRANSPOSED single-wave design (validated r4/r5, absmax 0.0078): one 64-lane
// wave owns 16 batch rows and the full H=64 chain; state^T = Waa @ a^T with
// weights as A (rows m, k pre-permuted by sigma) and state as B (n=batch).
// D layout (n=lane&15, m=4*lg+reg) IS the next step's sigma B-frag ->
// zero-cost feedback: no LDS, no barriers, no cross-lane ops in the loop.
// sigma_f(lg,j) = (j<4 ? 4*lg+j : 12+4*lg+j) + 32*f.
// Numerics: split-bf16 state (hi+lo), 3 products (WH*sH, WH*sL, WL*sH);
// x and Wy single bf16. x prefetched 4 steps ahead.

#define B_ 4096
#define T_ 256
#define E_ 27
#define H_ 64
#define WROW_ (H_ + E_)  // 91

typedef __bf16 bf16x8 __attribute__((ext_vector_type(8)));
typedef float f32x4 __attribute__((ext_vector_type(4)));
typedef unsigned int u32x4 __attribute__((ext_vector_type(4)));

static __device__ __forceinline__ unsigned pk2(float a, float b) {
  unsigned short ua = __builtin_bit_cast(unsigned short, (__bf16)a);
  unsigned short ub = __builtin_bit_cast(unsigned short, (__bf16)b);
  return (unsigned)ua | ((unsigned)ub << 16);
}
static __device__ __forceinline__ unsigned pkh(__bf16 a, __bf16 b) {
  unsigned short ua = __builtin_bit_cast(unsigned short, a);
  unsigned short ub = __builtin_bit_cast(unsigned short, b);
  return (unsigned)ua | ((unsigned)ub << 16);
}
static __device__ __forceinline__ float fast_tanh(float z) {
  // tanh(z) = 1 - 2/(exp(2z)+1); exp->inf / ->0 limits give +/-1 correctly
  float e = __expf(2.0f * z);
  float r = __builtin_amdgcn_rcpf(e + 1.0f);
  return __builtin_fmaf(-2.0f, r, 1.0f);
}
static __device__ __forceinline__ f32x4 MF(u32x4 a, u32x4 b, f32x4 c) {
  return __builtin_amdgcn_mfma_f32_16x16x32_bf16(
      __builtin_bit_cast(bf16x8, a), __builtin_bit_cast(bf16x8, b), c, 0, 0, 0);
}

__global__ __launch_bounds__(64)
__attribute__((amdgpu_waves_per_eu(1, 1))) void rnn_fused(
    const float* __restrict__ word, const float* __restrict__ Wa,
    const float* __restrict__ ba, const float* __restrict__ Wy,
    const float* __restrict__ by, float* __restrict__ out) {
  const int lane = threadIdx.x;
  const int p16 = lane & 15;  // batch row within group (n) / weight row (m)
  const int lg = lane >> 4;   // k-slot group
  const int rb = (int)blockIdx.x * 16;

  const float* const wrow = word + (size_t)(rb + p16) * (T_ * E_);
  float* const pout = out + (size_t)(rb + p16) * (T_ * E_);

  // ---- x prefetch sets (4-deep): pf0 = x(t=0) = 0; pf1..pf3 <- word[0..2] --
  float pf0[8], pf1[8], pf2[8], pf3[8];
#pragma unroll
  for (int k = 0; k < 8; ++k) {
    const int e = 8 * lg + k;
    pf0[k] = 0.f;
    pf1[k] = (e < E_) ? wrow[0 * E_ + 8 * lg + k] : 0.f;
    pf2[k] = (e < E_) ? wrow[1 * E_ + 8 * lg + k] : 0.f;
    pf3[k] = (e < E_) ? wrow[2 * E_ + 8 * lg + k] : 0.f;
  }

  // ---- weight fragments, pre-permuted by sigma ----
  u32x4 WH[4][2], WL[4][2], WX[4], WY[2][2];
  f32x4 BAv[4], BYv[2];
#pragma unroll
  for (int mt = 0; mt < 4; ++mt) {
    const float* base = Wa + (16 * mt + p16) * WROW_;
#pragma unroll
    for (int f = 0; f < 2; ++f) {
#pragma unroll
      for (int v = 0; v < 4; ++v) {
        const int j = 2 * v;
        const int c = ((j < 4) ? (4 * lg + j) : (12 + 4 * lg + j)) + 32 * f;
        const float w0 = base[c], w1 = base[c + 1];
        const __bf16 h0 = (__bf16)w0, h1 = (__bf16)w1;
        WH[mt][f][v] = pkh(h0, h1);
        WL[mt][f][v] = pk2(w0 - (float)h0, w1 - (float)h1);
      }
    }
#pragma unroll
    for (int v = 0; v < 4; ++v) {  // Wax, natural k = e
      const int e0 = 8 * lg + 2 * v, e1 = e0 + 1;
      const float w0 = (e0 < E_) ? base[H_ + e0] : 0.f;
      const float w1 = (e1 < E_) ? base[H_ + e1] : 0.f;
      WX[mt][v] = pk2(w0, w1);
    }
  }
#pragma unroll
  for (int my = 0; my < 2; ++my) {  // Wy rows e = 16*my + p16, sigma k-cols
    const int e = 16 * my + p16;
    const bool valid = (e < E_);
    const float* rp = Wy + e * H_;
#pragma unroll
    for (int f = 0; f < 2; ++f) {
#pragma unroll
      for (int v = 0; v < 4; ++v) {
        const int j = 2 * v;
        const int c = ((j < 4) ? (4 * lg + j) : (12 + 4 * lg + j)) + 32 * f;
        const float w0 = valid ? rp[c] : 0.f;
        const float w1 = valid ? rp[c + 1] : 0.f;
        WY[my][f][v] = pk2(w0, w1);
      }
    }
  }
#pragma unroll
  for (int mt = 0; mt < 4; ++mt) {
    f32x4 t;
#pragma unroll
    for (int r = 0; r < 4; ++r) t[r] = ba[16 * mt + 4 * lg + r];
    BAv[mt] = t;
  }
#pragma unroll
  for (int my = 0; my < 2; ++my) {
    f32x4 t;
#pragma unroll
    for (int r = 0; r < 4; ++r) {
      const int e = 16 * my + 4 * lg + r;
      t[r] = (e < E_) ? by[e] : 0.f;
    }
    BYv[my] = t;
  }

  // ---- state frags (sigma layout), a0 = 0 ----
  u32x4 sH0 = {0u, 0u, 0u, 0u}, sH1 = sH0, sL0 = sH0, sL1 = sH0;

#define STEP(t, PF)                                                           \
  {                                                                           \
    u32x4 xf;                                                                 \
    xf[0] = pk2(PF[0], PF[1]);                                                \
    xf[1] = pk2(PF[2], PF[3]);                                                \
    xf[2] = pk2(PF[4], PF[5]);                                                \
    xf[3] = pk2(PF[6], PF[7]);                                                \
    if ((t) + 3 < T_) { /* prefetch word[t+3] = x_{t+4}, consumed 4 steps on */\
      const float* p = wrow + ((t) + 3) * E_;                                 \
      _Pragma("unroll") for (int k = 0; k < 8; ++k) {                         \
        const int e = 8 * lg + k;                                             \
        PF[k] = (e < E_) ? p[8 * lg + k] : 0.f;                               \
      }                                                                       \
    }                                                                         \
    f32x4 acc[4];                                                             \
    _Pragma("unroll") for (int mt = 0; mt < 4; ++mt) {                        \
      f32x4 c0 = BAv[mt];                                                     \
      c0 = MF(WH[mt][0], sH0, c0);                                            \
      c0 = MF(WH[mt][1], sH1, c0);                                            \
      c0 = MF(WX[mt], xf, c0);                                                \
      f32x4 c1 = MF(WH[mt][0], sL0, (f32x4){0.f, 0.f, 0.f, 0.f});             \
      c1 = MF(WH[mt][1], sL1, c1);                                            \
      f32x4 c2 = MF(WL[mt][0], sH0, (f32x4){0.f, 0.f, 0.f, 0.f});             \
      c2 = MF(WL[mt][1], sH1, c2);                                            \
      acc[mt] = c0 + (c1 + c2);                                               \
    }                                                                         \
    unsigned hw[4][2], lw[4][2];                                              \
    _Pragma("unroll") for (int mt = 0; mt < 4; ++mt) {                        \
      const float t0 = fast_tanh(acc[mt][0]);                                 \
      const float t1 = fast_tanh(acc[mt][1]);                                 \
      const float t2 = fast_tanh(acc[mt][2]);                                 \
      const float t3 = fast_tanh(acc[mt][3]);                                 \
      const __bf16 h0 = (__bf16)t0, h1 = (__bf16)t1;                          \
      const __bf16 h2 = (__bf16)t2, h3 = (__bf16)t3;                          \
      hw[mt][0] = pkh(h0, h1);                                                \
      hw[mt][1] = pkh(h2, h3);                                                \
      lw[mt][0] = pk2(t0 - (float)h0, t1 - (float)h1);                        \
      lw[mt][1] = pk2(t2 - (float)h2, t3 - (float)h3);                        \
    }                                                                         \
    sH0[0] = hw[0][0]; sH0[1] = hw[0][1]; sH0[2] = hw[1][0]; sH0[3] = hw[1][1];\
    sH1[0] = hw[2][0]; sH1[1] = hw[2][1]; sH1[2] = hw[3][0]; sH1[3] = hw[3][1];\
    sL0[0] = lw[0][0]; sL0[1] = lw[0][1]; sL0[2] = lw[1][0]; sL0[3] = lw[1][1];\
    sL1[0] = lw[2][0]; sL1[1] = lw[2][1]; sL1[2] = lw[3][0]; sL1[3] = lw[3][1];\
    f32x4 y0 = BYv[0];                                                        \
    y0 = MF(WY[0][0], sH0, y0);                                               \
    y0 = MF(WY[0][1], sH1, y0);                                               \
    f32x4 y1 = BYv[1];                                                        \
    y1 = MF(WY[1][0], sH0, y1);                                               \
    y1 = MF(WY[1][1], sH1, y1);                                               \
    float* po = pout + (t)*E_;                                                \
    _Pragma("unroll") for (int r = 0; r < 4; ++r) po[4 * lg + r] = y0[r];     \
    _Pragma("unroll") for (int r = 0; r < 4; ++r) {                           \
      const int e = 16 + 4 * lg + r;                                          \
      if (e < E_) po[e] = y1[r];                                              \
    }                                                                         \
  }

  for (int t = 0; t < T_; t += 4) {
    // ---- AGPR pins, in-loop: weight frags live in AGPRs (MFMA reads A/B
    // from AGPR directly on gfx950); in-loop use-def makes spilling cost a
    // per-iteration store+load, so the allocator keeps them resident.
    // Empty asm = zero instructions.
#pragma unroll
    for (int mt = 0; mt < 4; ++mt) {
      asm volatile("" : "+a"(WH[mt][0]), "+a"(WH[mt][1]), "+a"(WL[mt][0]),
                        "+a"(WL[mt][1]), "+a"(WX[mt]));
    }
    asm volatile("" : "+a"(WY[0][0]), "+a"(WY[0][1]), "+a"(WY[1][0]),
                      "+a"(WY[1][1]));
    asm volatile("" : "+v"(BAv[0]), "+v"(BAv[1]), "+v"(BAv[2]), "+v"(BAv[3]),
                      "+v"(BYv[0]), "+v"(BYv[1]));

    STEP(t, pf0);
    STEP(t + 1, pf1);
    STEP(t + 2, pf2);
    STEP(t + 3, pf3);
  }
#undef STEP
}

extern "C" void kernel_launch(void* const* d_in, const int* in_sizes, int n_in,
                              void* d_out, int out_size, void* d_ws,
                              size_t ws_size, hipStream_t stream) {
  const float* word = (const float*)d_in[0];
  const float* Wa = (const float*)d_in[1];
  const float* ba = (const float*)d_in[2];
  const float* Wy = (const float*)d_in[3];
  const float* by = (const float*)d_in[4];
  float* out = (float*)d_out;
  rnn_fused<<<dim3(B_ / 16), dim3(64), 0, stream>>>(word, Wa, ba, Wy, by, out);
}

// Round 7
// 224.961 us; speedup vs baseline: 1.1553x; 1.1553x over previous
//
#include <hip/hip_runtime.h>
#include <stdint.h>

// RNN1: B=4096,T=256,E=27,H=64.
// a_{t+1} = tanh(a_t @ Waa^T + x_t @ Wax^T + ba), x_t = word[:,t-1,:] (0 at t=0)
// y[:,t,:] = a_{t+1} @ Wy^T + by
//
// Round 7: LDS-staged I/O. r4-r6 invariance (258-268us across register-only /
// AGPR-pinned variants) killed the spill theory; the invariant is ~15 scattered
// global mem instrs/step on the serial chain (8 x-loads + 7 y-stores, lanes
// 27KB apart -> 32-48 lines per instr, in-order vmcnt retirement). This round:
//  - x: inline-asm global_load_dwordx4 issued one GROUP (4 steps) early into
//    regs (asm pins issue point - cannot be sunk), ds_write into an 8-slot LDS
//    ring at next group top (vmcnt(0) there has a full group of slack); per
//    step 2 aligned ds_read_b128, prefetched 1 step ahead.
//  - y: per step 2 aligned ds_write_b128 into a 4-slot ring; flushed to global
//    as float4 chunks once per 4 steps (4-step register-reuse slack).
//  - single wave per block -> LDS needs NO barriers; compute core bit-identical
//    to validated r6 (sigma layout, split-bf16 hi/lo, same op order).
//
// TRANSPOSED single-wave design (validated r4-r6, absmax 0.0078125): one
// 64-lane wave owns 16 batch rows and the full H=64 chain; state^T = Waa @ a^T,
// weights as A (rows m, k pre-permuted by sigma), state as B (n=batch).
// D layout (n=lane&15, m=4*lg+reg) IS the next step's sigma B-frag ->
// zero-cost feedback. sigma_f(lg,j) = (j<4 ? 4*lg+j : 12+4*lg+j) + 32*f.

#define B_ 4096
#define T_ 256
#define E_ 27
#define H_ 64
#define WROW_ (H_ + E_)  // 91

typedef __bf16 bf16x8 __attribute__((ext_vector_type(8)));
typedef float f32x4 __attribute__((ext_vector_type(4)));
typedef unsigned int u32x4 __attribute__((ext_vector_type(4)));

struct __attribute__((packed)) f4a { float v[4]; };  // 4B-aligned global float4

static __device__ __forceinline__ unsigned pk2(float a, float b) {
  unsigned short ua = __builtin_bit_cast(unsigned short, (__bf16)a);
  unsigned short ub = __builtin_bit_cast(unsigned short, (__bf16)b);
  return (unsigned)ua | ((unsigned)ub << 16);
}
static __device__ __forceinline__ unsigned pkh(__bf16 a, __bf16 b) {
  unsigned short ua = __builtin_bit_cast(unsigned short, a);
  unsigned short ub = __builtin_bit_cast(unsigned short, b);
  return (unsigned)ua | ((unsigned)ub << 16);
}
static __device__ __forceinline__ float fast_tanh(float z) {
  // tanh(z) = 1 - 2/(exp(2z)+1); exp->inf / ->0 limits give +/-1 correctly
  float e = __expf(2.0f * z);
  float r = __builtin_amdgcn_rcpf(e + 1.0f);
  return __builtin_fmaf(-2.0f, r, 1.0f);
}
static __device__ __forceinline__ f32x4 MF(u32x4 a, u32x4 b, f32x4 c) {
  return __builtin_amdgcn_mfma_f32_16x16x32_bf16(
      __builtin_bit_cast(bf16x8, a), __builtin_bit_cast(bf16x8, b), c, 0, 0, 0);
}

__global__ __launch_bounds__(64)
__attribute__((amdgpu_waves_per_eu(1, 1))) void rnn_fused(
    const float* __restrict__ word, const float* __restrict__ Wa,
    const float* __restrict__ ba, const float* __restrict__ Wy,
    const float* __restrict__ by, float* __restrict__ out) {
  // x ring: slot s holds x for step t (t%8==s), i.e. word[:,t-1,:]. 36-pad:
  // bank = (4*p16 + 8*lg + const) mod 32 -> only (p16,p16+8) collide = 2-way
  // (free). cols 28..35 stay zero forever (xf cols 27..31 hit zero weights;
  // operands must be finite, hence the zero-init).
  __shared__ __align__(16) float xs[8][16][36];
  __shared__ __align__(16) float ys[4][16][36];

  const int lane = threadIdx.x;
  const int p16 = lane & 15;  // batch row within group (n) / weight row (m)
  const int lg = lane >> 4;   // k-slot group / step-within-group for staging
  const int rb = (int)blockIdx.x * 16;

  const float* const wbase = word + (size_t)(rb + p16) * (T_ * E_);
  float* const obase = out + (size_t)(rb + p16) * (T_ * E_);

  {  // zero xs once (single wave: ordering vs later ds ops is automatic)
    float* xz = &xs[0][0][0];
    for (int i = lane; i < 8 * 16 * 36; i += 64) xz[i] = 0.f;
  }

  // ---- weight fragments, pre-permuted by sigma (identical to r6) ----
  u32x4 WH[4][2], WL[4][2], WX[4], WY[2][2];
  f32x4 BAv[4], BYv[2];
#pragma unroll
  for (int mt = 0; mt < 4; ++mt) {
    const float* base = Wa + (16 * mt + p16) * WROW_;
#pragma unroll
    for (int f = 0; f < 2; ++f) {
#pragma unroll
      for (int v = 0; v < 4; ++v) {
        const int j = 2 * v;
        const int c = ((j < 4) ? (4 * lg + j) : (12 + 4 * lg + j)) + 32 * f;
        const float w0 = base[c], w1 = base[c + 1];
        const __bf16 h0 = (__bf16)w0, h1 = (__bf16)w1;
        WH[mt][f][v] = pkh(h0, h1);
        WL[mt][f][v] = pk2(w0 - (float)h0, w1 - (float)h1);
      }
    }
#pragma unroll
    for (int v = 0; v < 4; ++v) {  // Wax, natural k = e
      const int e0 = 8 * lg + 2 * v, e1 = e0 + 1;
      const float w0 = (e0 < E_) ? base[H_ + e0] : 0.f;
      const float w1 = (e1 < E_) ? base[H_ + e1] : 0.f;
      WX[mt][v] = pk2(w0, w1);
    }
  }
#pragma unroll
  for (int my = 0; my < 2; ++my) {
    const int e = 16 * my + p16;
    const bool valid = (e < E_);
    const float* rp = Wy + e * H_;
#pragma unroll
    for (int f = 0; f < 2; ++f) {
#pragma unroll
      for (int v = 0; v < 4; ++v) {
        const int j = 2 * v;
        const int c = ((j < 4) ? (4 * lg + j) : (12 + 4 * lg + j)) + 32 * f;
        const float w0 = valid ? rp[c] : 0.f;
        const float w1 = valid ? rp[c + 1] : 0.f;
        WY[my][f][v] = pk2(w0, w1);
      }
    }
  }
#pragma unroll
  for (int mt = 0; mt < 4; ++mt) {
    f32x4 t;
#pragma unroll
    for (int r = 0; r < 4; ++r) t[r] = ba[16 * mt + 4 * lg + r];
    BAv[mt] = t;
  }
#pragma unroll
  for (int my = 0; my < 2; ++my) {
    f32x4 t;
#pragma unroll
    for (int r = 0; r < 4; ++r) {
      const int e = 16 * my + 4 * lg + r;
      t[r] = (e < E_) ? by[e] : 0.f;
    }
    BYv[my] = t;
  }

  // ---- x staging: this lane owns step ts+lg (word row ts+lg-1), 7 float4
  // chunks covering 27 floats (chunk 6 overruns 1 float into the next word
  // row: in-bounds since staged word rows are <= 254). Inline-asm loads pin
  // the issue point (cannot be sunk to the consumer). ----
  f32x4 Rg[7];
#define X_ISSUE(ts)                                                         \
  {                                                                         \
    const int st_ = (ts) + lg;                                              \
    if (st_ >= 1 && st_ < T_) {                                             \
      const float* p_ = wbase + (st_ - 1) * E_;                             \
      _Pragma("unroll") for (int c = 0; c < 7; ++c) {                       \
        asm volatile("global_load_dwordx4 %0, %1, off"                      \
                     : "=v"(Rg[c]) : "v"(p_ + 4 * c) : "memory");           \
      }                                                                     \
    }                                                                       \
  }
  // Write staged regs (issued one group ago) into the ring. vmcnt(0) here has
  // a full group (~4 steps) of slack; it also retires old flush stores.
#define X_WRITE(ts)                                                         \
  {                                                                         \
    asm volatile("s_waitcnt vmcnt(0)" ::: "memory");                        \
    __builtin_amdgcn_sched_barrier(0);                                      \
    const int st_ = (ts) + lg;                                              \
    if (st_ >= 1 && st_ < T_) {                                             \
      float* d_ = &xs[st_ & 7][p16][0];                                     \
      _Pragma("unroll") for (int c = 0; c < 7; ++c)                         \
        *(f32x4*)(d_ + 4 * c) = Rg[c];                                      \
    }                                                                       \
  }
  // y flush: this lane owns step tb+lg (ring slot lg since tb%4==0), 6 full
  // float4 chunks + a 3-float tail. Plain stores; register reuse gives the
  // compiler a 4-step slack for its waitcnts.
#define Y_FLUSH(tb)                                                         \
  {                                                                         \
    const float* s_ = &ys[lg][p16][0];                                      \
    float* d_ = obase + ((tb) + lg) * E_;                                   \
    _Pragma("unroll") for (int c = 0; c < 6; ++c) {                         \
      f32x4 v_ = *(const f32x4*)(s_ + 4 * c);                               \
      f4a o_;                                                               \
      o_.v[0] = v_[0]; o_.v[1] = v_[1]; o_.v[2] = v_[2]; o_.v[3] = v_[3];   \
      *(f4a*)(d_ + 4 * c) = o_;                                             \
    }                                                                       \
    f32x4 v6_ = *(const f32x4*)(s_ + 24);                                   \
    d_[24] = v6_[0]; d_[25] = v6_[1]; d_[26] = v6_[2];                      \
  }

  // ---- prologue: stage steps 0..3 (step 0 = zeros via memset), issue 4..7,
  // preload x for step 0 ----
  X_ISSUE(0);
  X_WRITE(0);
  X_ISSUE(4);
  f32x4 xc0, xc1;
  {
    const float* xp = &xs[0][p16][8 * lg];
    xc0 = *(const f32x4*)xp;
    xc1 = *(const f32x4*)(xp + 4);
  }

  // ---- state frags (sigma layout), a0 = 0 ----
  u32x4 sH0 = {0u, 0u, 0u, 0u}, sH1 = sH0, sL0 = sH0, sL1 = sH0;

#define STEP(t)                                                               \
  {                                                                           \
    u32x4 xf;                                                                 \
    xf[0] = pk2(xc0[0], xc0[1]);                                              \
    xf[1] = pk2(xc0[2], xc0[3]);                                              \
    xf[2] = pk2(xc1[0], xc1[1]);                                              \
    xf[3] = pk2(xc1[2], xc1[3]);                                              \
    if ((t) + 1 < T_) { /* prefetch next step's x from LDS */                 \
      const float* xp_ = &xs[((t) + 1) & 7][p16][8 * lg];                     \
      xc0 = *(const f32x4*)xp_;                                               \
      xc1 = *(const f32x4*)(xp_ + 4);                                         \
    }                                                                         \
    f32x4 acc[4];                                                             \
    _Pragma("unroll") for (int mt = 0; mt < 4; ++mt) {                        \
      f32x4 c0 = BAv[mt];                                                     \
      c0 = MF(WH[mt][0], sH0, c0);                                            \
      c0 = MF(WH[mt][1], sH1, c0);                                            \
      c0 = MF(WX[mt], xf, c0);                                                \
      f32x4 c1 = MF(WH[mt][0], sL0, (f32x4){0.f, 0.f, 0.f, 0.f});             \
      c1 = MF(WH[mt][1], sL1, c1);                                            \
      f32x4 c2 = MF(WL[mt][0], sH0, (f32x4){0.f, 0.f, 0.f, 0.f});             \
      c2 = MF(WL[mt][1], sH1, c2);                                            \
      acc[mt] = c0 + (c1 + c2);                                               \
    }                                                                         \
    unsigned hw[4][2], lw[4][2];                                              \
    _Pragma("unroll") for (int mt = 0; mt < 4; ++mt) {                        \
      const float t0_ = fast_tanh(acc[mt][0]);                                \
      const float t1_ = fast_tanh(acc[mt][1]);                                \
      const float t2_ = fast_tanh(acc[mt][2]);                                \
      const float t3_ = fast_tanh(acc[mt][3]);                                \
      const __bf16 h0 = (__bf16)t0_, h1 = (__bf16)t1_;                        \
      const __bf16 h2 = (__bf16)t2_, h3 = (__bf16)t3_;                        \
      hw[mt][0] = pkh(h0, h1);                                                \
      hw[mt][1] = pkh(h2, h3);                                                \
      lw[mt][0] = pk2(t0_ - (float)h0, t1_ - (float)h1);                      \
      lw[mt][1] = pk2(t2_ - (float)h2, t3_ - (float)h3);                      \
    }                                                                         \
    sH0[0] = hw[0][0]; sH0[1] = hw[0][1]; sH0[2] = hw[1][0]; sH0[3] = hw[1][1];\
    sH1[0] = hw[2][0]; sH1[1] = hw[2][1]; sH1[2] = hw[3][0]; sH1[3] = hw[3][1];\
    sL0[0] = lw[0][0]; sL0[1] = lw[0][1]; sL0[2] = lw[1][0]; sL0[3] = lw[1][1];\
    sL1[0] = lw[2][0]; sL1[1] = lw[2][1]; sL1[2] = lw[3][0]; sL1[3] = lw[3][1];\
    f32x4 y0 = BYv[0];                                                        \
    y0 = MF(WY[0][0], sH0, y0);                                               \
    y0 = MF(WY[0][1], sH1, y0);                                               \
    f32x4 y1 = BYv[1];                                                        \
    y1 = MF(WY[1][0], sH0, y1);                                               \
    y1 = MF(WY[1][1], sH1, y1);                                               \
    *(f32x4*)&ys[(t) & 3][p16][4 * lg] = y0;                                  \
    *(f32x4*)&ys[(t) & 3][p16][16 + 4 * lg] = y1;                             \
  }

  for (int t0 = 0; t0 < T_; t0 += 4) {
    // AGPR/VGPR pins (r6): keep weights resident in AGPRs, biases in VGPRs.
#pragma unroll
    for (int mt = 0; mt < 4; ++mt) {
      asm volatile("" : "+a"(WH[mt][0]), "+a"(WH[mt][1]), "+a"(WL[mt][0]),
                        "+a"(WL[mt][1]), "+a"(WX[mt]));
    }
    asm volatile("" : "+a"(WY[0][0]), "+a"(WY[0][1]), "+a"(WY[1][0]),
                      "+a"(WY[1][1]));
    asm volatile("" : "+v"(BAv[0]), "+v"(BAv[1]), "+v"(BAv[2]), "+v"(BAv[3]),
                      "+v"(BYv[0]), "+v"(BYv[1]));

    X_WRITE(t0 + 4);            // stage steps t0+4..t0+7 (loaded last group)
    X_ISSUE(t0 + 8);            // issue next group's loads (full-group slack)
    if (t0 > 0) Y_FLUSH(t0 - 4);  // flush previous group's y

    STEP(t0);
    STEP(t0 + 1);
    STEP(t0 + 2);
    STEP(t0 + 3);
  }
  Y_FLUSH(T_ - 4);
#undef STEP
#undef X_ISSUE
#undef X_WRITE
#undef Y_FLUSH
}

extern "C" void kernel_launch(void* const* d_in, const int* in_sizes, int n_in,
                              void* d_out, int out_size, void* d_ws,
                              size_t ws_size, hipStream_t stream) {
  const float* word = (const float*)d_in[0];
  const float* Wa = (const float*)d_in[1];
  const float* ba = (const float*)d_in[2];
  const float* Wy = (const float*)d_in[3];
  const float* by = (const float*)d_in[4];
  float* out = (float*)d_out;
  rnn_fused<<<dim3(B_ / 16), dim3(64), 0, stream>>>(word, Wa, ba, Wy, by, out);
}

// Round 9
// 168.109 us; speedup vs baseline: 1.5459x; 1.3382x over previous
//
#include <hip/hip_runtime.h>
#include <stdint.h>

// RNN1: B=4096,T=256,E=27,H=64.
// a_{t+1} = tanh(a_t @ Waa^T + x_t @ Wax^T + ba), x_t = word[:,t-1,:] (0 at t=0)
// y[:,t,:] = a_{t+1} @ Wy^T + by
//
// Round 9 = round 8 (C-chained MFMAs + cvt_pk packs; first-call-valid at
// 166us) + determinism fix: r8 diverged ONLY post-timing (graph replays) ->
// timing race. Cause: X_ISSUE's asm global_loads are invisible to the
// compiler's waitcnt model; X_WRITE's ds_writes read Rg while the NEXT
// group's loads (issued right after) could return into the same Rg before
// the queued ds_writes consume it (DS data is read at execute, not issue).
// Fix: DOUBLE-BUFFERED staging regs Rg[0]/Rg[1] alternating by group parity
// (write R[p], issue R[p^1]; reuse gap = one full group) + lgkmcnt(0) fence
// after the ds_writes. Group loop unrolled x2 so parity is compile-time.
//
// TRANSPOSED single-wave design (validated r4-r8, absmax 0.0078125): one
// 64-lane wave owns 16 batch rows and the full H=64 chain; state^T = Waa@a^T,
// weights as A (rows m, k pre-permuted by sigma), state as B (n=batch).
// D layout (n=lane&15, m=4*lg+reg) IS the next step's sigma B-frag ->
// zero-cost feedback. sigma_f(lg,j) = (j<4 ? 4*lg+j : 12+4*lg+j) + 32*f.

#define B_ 4096
#define T_ 256
#define E_ 27
#define H_ 64
#define WROW_ (H_ + E_)  // 91

typedef __bf16 bf16x8 __attribute__((ext_vector_type(8)));
typedef float f32x4 __attribute__((ext_vector_type(4)));
typedef unsigned int u32x4 __attribute__((ext_vector_type(4)));

struct __attribute__((packed)) f4a { float v[4]; };  // 4B-aligned global float4

static __device__ __forceinline__ unsigned pk2(float a, float b) {
  unsigned short ua = __builtin_bit_cast(unsigned short, (__bf16)a);
  unsigned short ub = __builtin_bit_cast(unsigned short, (__bf16)b);
  return (unsigned)ua | ((unsigned)ub << 16);
}
static __device__ __forceinline__ unsigned pkh(__bf16 a, __bf16 b) {
  unsigned short ua = __builtin_bit_cast(unsigned short, a);
  unsigned short ub = __builtin_bit_cast(unsigned short, b);
  return (unsigned)ua | ((unsigned)ub << 16);
}
// v_cvt_pk_bf16_f32: dst = [bf16(hi)|bf16(lo)], RNE (same as (__bf16) cast).
static __device__ __forceinline__ unsigned cvtpk(float lo, float hi) {
  unsigned r;
  asm("v_cvt_pk_bf16_f32 %0, %1, %2" : "=v"(r) : "v"(lo), "v"(hi));
  return r;
}
// lo-residual pack: t - f32(RNE16(t)) is exact in f32.
static __device__ __forceinline__ unsigned lopk(unsigned hpk, float t0, float t1) {
  const float f0 = __builtin_bit_cast(float, hpk << 16);
  const float f1 = __builtin_bit_cast(float, hpk & 0xffff0000u);
  return cvtpk(t0 - f0, t1 - f1);
}
static __device__ __forceinline__ float fast_tanh(float z) {
  // tanh(z) = 1 - 2/(exp(2z)+1); exp->inf / ->0 limits give +/-1 correctly
  float e = __expf(2.0f * z);
  float r = __builtin_amdgcn_rcpf(e + 1.0f);
  return __builtin_fmaf(-2.0f, r, 1.0f);
}
static __device__ __forceinline__ f32x4 MF(u32x4 a, u32x4 b, f32x4 c) {
  return __builtin_amdgcn_mfma_f32_16x16x32_bf16(
      __builtin_bit_cast(bf16x8, a), __builtin_bit_cast(bf16x8, b), c, 0, 0, 0);
}

__global__ __launch_bounds__(64)
__attribute__((amdgpu_waves_per_eu(1, 1))) void rnn_fused(
    const float* __restrict__ word, const float* __restrict__ Wa,
    const float* __restrict__ ba, const float* __restrict__ Wy,
    const float* __restrict__ by, float* __restrict__ out) {
  // x ring: slot s holds x for step t (t%8==s) = word[:,t-1,:]; 36-pad ->
  // worst LDS aliasing 2-way (free). cols 28..35 stay zero forever.
  __shared__ __align__(16) float xs[8][16][36];
  __shared__ __align__(16) float ys[4][16][36];

  const int lane = threadIdx.x;
  const int p16 = lane & 15;  // batch row within group (n) / weight row (m)
  const int lg = lane >> 4;   // k-slot group / step-within-group for staging
  const int rb = (int)blockIdx.x * 16;

  const float* const wbase = word + (size_t)(rb + p16) * (T_ * E_);
  float* const obase = out + (size_t)(rb + p16) * (T_ * E_);

  {  // zero xs once (single wave: ordering vs later ds ops is automatic)
    float* xz = &xs[0][0][0];
    for (int i = lane; i < 8 * 16 * 36; i += 64) xz[i] = 0.f;
  }

  // ---- weight fragments, pre-permuted by sigma (identical to r6-r8) ----
  u32x4 WH[4][2], WL[4][2], WX[4], WY[2][2];
  f32x4 BAv[4], BYv[2];
#pragma unroll
  for (int mt = 0; mt < 4; ++mt) {
    const float* base = Wa + (16 * mt + p16) * WROW_;
#pragma unroll
    for (int f = 0; f < 2; ++f) {
#pragma unroll
      for (int v = 0; v < 4; ++v) {
        const int j = 2 * v;
        const int c = ((j < 4) ? (4 * lg + j) : (12 + 4 * lg + j)) + 32 * f;
        const float w0 = base[c], w1 = base[c + 1];
        const __bf16 h0 = (__bf16)w0, h1 = (__bf16)w1;
        WH[mt][f][v] = pkh(h0, h1);
        WL[mt][f][v] = pk2(w0 - (float)h0, w1 - (float)h1);
      }
    }
#pragma unroll
    for (int v = 0; v < 4; ++v) {  // Wax, natural k = e
      const int e0 = 8 * lg + 2 * v, e1 = e0 + 1;
      const float w0 = (e0 < E_) ? base[H_ + e0] : 0.f;
      const float w1 = (e1 < E_) ? base[H_ + e1] : 0.f;
      WX[mt][v] = pk2(w0, w1);
    }
  }
#pragma unroll
  for (int my = 0; my < 2; ++my) {
    const int e = 16 * my + p16;
    const bool valid = (e < E_);
    const float* rp = Wy + e * H_;
#pragma unroll
    for (int f = 0; f < 2; ++f) {
#pragma unroll
      for (int v = 0; v < 4; ++v) {
        const int j = 2 * v;
        const int c = ((j < 4) ? (4 * lg + j) : (12 + 4 * lg + j)) + 32 * f;
        const float w0 = valid ? rp[c] : 0.f;
        const float w1 = valid ? rp[c + 1] : 0.f;
        WY[my][f][v] = pk2(w0, w1);
      }
    }
  }
#pragma unroll
  for (int mt = 0; mt < 4; ++mt) {
    f32x4 t;
#pragma unroll
    for (int r = 0; r < 4; ++r) t[r] = ba[16 * mt + 4 * lg + r];
    BAv[mt] = t;
  }
#pragma unroll
  for (int my = 0; my < 2; ++my) {
    f32x4 t;
#pragma unroll
    for (int r = 0; r < 4; ++r) {
      const int e = 16 * my + 4 * lg + r;
      t[r] = (e < E_) ? by[e] : 0.f;
    }
    BYv[my] = t;
  }

  // ---- x staging, DOUBLE-BUFFERED regs: lane owns step ts+lg (word row
  // ts+lg-1), 7 float4 chunks (chunk 6 overruns 1 float within this batch
  // row's T*E: staged rows <= 254). P is a compile-time parity. ----
  f32x4 Rg[2][7];
#define X_ISSUE(ts, P)                                                      \
  {                                                                         \
    const int st_ = (ts) + lg;                                              \
    if (st_ >= 1 && st_ < T_) {                                             \
      const float* p_ = wbase + (st_ - 1) * E_;                             \
      _Pragma("unroll") for (int c = 0; c < 7; ++c) {                       \
        asm volatile("global_load_dwordx4 %0, %1, off"                      \
                     : "=v"(Rg[P][c]) : "v"(p_ + 4 * c) : "memory");        \
      }                                                                     \
    }                                                                       \
  }
  // vmcnt(0): staged loads (issued one group ago) have landed in Rg[P].
  // lgkmcnt(0) after: the ds_writes have CONSUMED Rg[P] before anything else
  // (DS data regs are read at execute, not issue).
#define X_WRITE(ts, P)                                                      \
  {                                                                         \
    asm volatile("s_waitcnt vmcnt(0)" ::: "memory");                        \
    __builtin_amdgcn_sched_barrier(0);                                      \
    const int st_ = (ts) + lg;                                              \
    if (st_ >= 1 && st_ < T_) {                                             \
      float* d_ = &xs[st_ & 7][p16][0];                                     \
      _Pragma("unroll") for (int c = 0; c < 7; ++c)                         \
        *(f32x4*)(d_ + 4 * c) = Rg[P][c];                                   \
    }                                                                       \
    asm volatile("s_waitcnt lgkmcnt(0)" ::: "memory");                      \
    __builtin_amdgcn_sched_barrier(0);                                      \
  }
#define Y_FLUSH(tb)                                                         \
  {                                                                         \
    const float* s_ = &ys[lg][p16][0];                                      \
    float* d_ = obase + ((tb) + lg) * E_;                                   \
    _Pragma("unroll") for (int c = 0; c < 6; ++c) {                         \
      f32x4 v_ = *(const f32x4*)(s_ + 4 * c);                               \
      f4a o_;                                                               \
      o_.v[0] = v_[0]; o_.v[1] = v_[1]; o_.v[2] = v_[2]; o_.v[3] = v_[3];   \
      *(f4a*)(d_ + 4 * c) = o_;                                             \
    }                                                                       \
    f32x4 v6_ = *(const f32x4*)(s_ + 24);                                   \
    d_[24] = v6_[0]; d_[25] = v6_[1]; d_[26] = v6_[2];                      \
  }

  // ---- prologue: I(0)->R0, W(0)<-R0, I(4)->R1; preload xc = x for step 1 --
  X_ISSUE(0, 0);
  X_WRITE(0, 0);
  X_ISSUE(4, 1);
  f32x4 xc0, xc1;
  {
    const float* xp = &xs[1][p16][8 * lg];
    xc0 = *(const f32x4*)xp;
    xc1 = *(const f32x4*)(xp + 4);
  }

  // ---- loop-carried state: sH/sL frags (sigma layout), xf = packed x_t ----
  u32x4 sH0 = {0u, 0u, 0u, 0u}, sH1 = sH0, sL0 = sH0, sL1 = sH0;
  u32x4 xf = {0u, 0u, 0u, 0u};  // x_0 = 0 (bf16 zeros)

#define STEP(t)                                                               \
  {                                                                           \
    /* state C-chains: 7 MFMAs per mt through the C input (accumulator        \
       forwarding); 4 chains interleaved; sL terms last (lo-shadow slack). */ \
    f32x4 z0 = MF(WH[0][0], sH0, BAv[0]);                                     \
    f32x4 z1 = MF(WH[1][0], sH0, BAv[1]);                                     \
    f32x4 z2 = MF(WH[2][0], sH0, BAv[2]);                                     \
    f32x4 z3 = MF(WH[3][0], sH0, BAv[3]);                                     \
    z0 = MF(WH[0][1], sH1, z0);                                               \
    z1 = MF(WH[1][1], sH1, z1);                                               \
    z2 = MF(WH[2][1], sH1, z2);                                               \
    z3 = MF(WH[3][1], sH1, z3);                                               \
    z0 = MF(WL[0][0], sH0, z0);                                               \
    z1 = MF(WL[1][0], sH0, z1);                                               \
    z2 = MF(WL[2][0], sH0, z2);                                               \
    z3 = MF(WL[3][0], sH0, z3);                                               \
    z0 = MF(WL[0][1], sH1, z0);                                               \
    z1 = MF(WL[1][1], sH1, z1);                                               \
    z2 = MF(WL[2][1], sH1, z2);                                               \
    z3 = MF(WL[3][1], sH1, z3);                                               \
    z0 = MF(WX[0], xf, z0);                                                   \
    z1 = MF(WX[1], xf, z1);                                                   \
    z2 = MF(WX[2], xf, z2);                                                   \
    z3 = MF(WX[3], xf, z3);                                                   \
    z0 = MF(WH[0][0], sL0, z0);                                               \
    z1 = MF(WH[1][0], sL0, z1);                                               \
    z2 = MF(WH[2][0], sL0, z2);                                               \
    z3 = MF(WH[3][0], sL0, z3);                                               \
    z0 = MF(WH[0][1], sL1, z0);                                               \
    z1 = MF(WH[1][1], sL1, z1);                                               \
    z2 = MF(WH[2][1], sL1, z2);                                               \
    z3 = MF(WH[3][1], sL1, z3);                                               \
    /* tanh (5-op chain per value) + 1-instr RNE hi-pack -> new sH */         \
    float tv[16];                                                             \
    _Pragma("unroll") for (int r = 0; r < 4; ++r) tv[r] = fast_tanh(z0[r]);   \
    _Pragma("unroll") for (int r = 0; r < 4; ++r) tv[4 + r] = fast_tanh(z1[r]);\
    _Pragma("unroll") for (int r = 0; r < 4; ++r) tv[8 + r] = fast_tanh(z2[r]);\
    _Pragma("unroll") for (int r = 0; r < 4; ++r) tv[12 + r] = fast_tanh(z3[r]);\
    sH0[0] = cvtpk(tv[0], tv[1]);                                             \
    sH0[1] = cvtpk(tv[2], tv[3]);                                             \
    sH0[2] = cvtpk(tv[4], tv[5]);                                             \
    sH0[3] = cvtpk(tv[6], tv[7]);                                             \
    sH1[0] = cvtpk(tv[8], tv[9]);                                             \
    sH1[1] = cvtpk(tv[10], tv[11]);                                           \
    sH1[2] = cvtpk(tv[12], tv[13]);                                           \
    sH1[3] = cvtpk(tv[14], tv[15]);                                           \
    /* next x pack (off-path; needed ~5 MFMAs into next step) */              \
    xf[0] = cvtpk(xc0[0], xc0[1]);                                            \
    xf[1] = cvtpk(xc0[2], xc0[3]);                                            \
    xf[2] = cvtpk(xc1[0], xc1[1]);                                            \
    xf[3] = cvtpk(xc1[2], xc1[3]);                                            \
    if ((t) + 2 < T_) { /* prefetch x for step t+2 (full step of slack) */    \
      const float* xp_ = &xs[((t) + 2) & 7][p16][8 * lg];                     \
      xc0 = *(const f32x4*)xp_;                                               \
      xc1 = *(const f32x4*)(xp_ + 4);                                         \
    }                                                                         \
    /* lo-residual split in the shadow (sL consumed late next step) */        \
    sL0[0] = lopk(sH0[0], tv[0], tv[1]);                                      \
    sL0[1] = lopk(sH0[1], tv[2], tv[3]);                                      \
    sL0[2] = lopk(sH0[2], tv[4], tv[5]);                                      \
    sL0[3] = lopk(sH0[3], tv[6], tv[7]);                                      \
    sL1[0] = lopk(sH1[0], tv[8], tv[9]);                                      \
    sL1[1] = lopk(sH1[1], tv[10], tv[11]);                                    \
    sL1[2] = lopk(sH1[2], tv[12], tv[13]);                                    \
    sL1[3] = lopk(sH1[3], tv[14], tv[15]);                                    \
    /* y (off-path): C-chained pairs, stash in LDS ring */                    \
    f32x4 y0 = MF(WY[0][1], sH1, MF(WY[0][0], sH0, BYv[0]));                  \
    f32x4 y1 = MF(WY[1][1], sH1, MF(WY[1][0], sH0, BYv[1]));                  \
    *(f32x4*)&ys[(t) & 3][p16][4 * lg] = y0;                                  \
    *(f32x4*)&ys[(t) & 3][p16][16 + 4 * lg] = y1;                             \
  }

#define GROUP(t0, PW, PI)                                                     \
  {                                                                           \
    _Pragma("unroll") for (int mt = 0; mt < 4; ++mt) {                        \
      asm volatile("" : "+a"(WH[mt][0]), "+a"(WH[mt][1]), "+a"(WL[mt][0]),    \
                        "+a"(WL[mt][1]), "+a"(WX[mt]));                       \
    }                                                                         \
    asm volatile("" : "+a"(WY[0][0]), "+a"(WY[0][1]), "+a"(WY[1][0]),         \
                      "+a"(WY[1][1]));                                        \
    asm volatile("" : "+v"(BAv[0]), "+v"(BAv[1]), "+v"(BAv[2]), "+v"(BAv[3]), \
                      "+v"(BYv[0]), "+v"(BYv[1]));                            \
    X_WRITE((t0) + 4, PW); /* stage steps t0+4..t0+7 (issued last group) */   \
    X_ISSUE((t0) + 8, PI); /* issue next group into the OTHER buffer */       \
    if ((t0) > 0) Y_FLUSH((t0) - 4);                                          \
    STEP(t0);                                                                 \
    STEP((t0) + 1);                                                           \
    STEP((t0) + 2);                                                           \
    STEP((t0) + 3);                                                           \
  }

  for (int t0 = 0; t0 < T_; t0 += 8) {
    GROUP(t0, 1, 0);      // write R1 (issued in prologue / prev odd group)
    GROUP(t0 + 4, 0, 1);  // write R0, issue R1
  }
  Y_FLUSH(T_ - 4);
#undef GROUP
#undef STEP
#undef X_ISSUE
#undef X_WRITE
#undef Y_FLUSH
}

extern "C" void kernel_launch(void* const* d_in, const int* in_sizes, int n_in,
                              void* d_out, int out_size, void* d_ws,
                              size_t ws_size, hipStream_t stream) {
  const float* word = (const float*)d_in[0];
  const float* Wa = (const float*)d_in[1];
  const float* ba = (const float*)d_in[2];
  const float* Wy = (const float*)d_in[3];
  const float* by = (const float*)d_in[4];
  float* out = (float*)d_out;
  rnn_fused<<<dim3(B_ / 16), dim3(64), 0, stream>>>(word, Wa, ba, Wy, by, out);
}